// Round 1
// baseline (106.030 us; speedup 1.0000x reference)
//
#include <hip/hip_runtime.h>
#include <math.h>

// ---------------- problem constants ----------------
namespace {
constexpr int BATCH = 4;
constexpr int IMG   = 192;
constexpr int NP1   = 4096;   // 64*64 full-res patches per image
constexpr int MALL  = 5376;   // 4096 + 1024 + 256 candidate patches
constexpr int RS    = 28;     // row stride: 27 values + |c|^2 slot
constexpr int E_TN = 2, E_BLOCK = 256, E_NPB = 512, E_NT = 8, E_MS = 32, E_MC = 168;

// gaussian kernel constants (float32 images of the numpy float32 values)
#define GA 0.27406862f   // gauss1d(1.0) edge
#define GB 0.45186276f   // gauss1d(1.0) center
#define RC 0.33277732f   // gauss1d(10.0) edge
#define RD 0.33444537f   // gauss1d(10.0) center

__device__ __forceinline__ void conv3(const float in[9], const float k[9], float out[9]) {
#pragma unroll
  for (int y = 0; y < 3; ++y)
#pragma unroll
    for (int x = 0; x < 3; ++x) {
      float s = 0.f;
#pragma unroll
      for (int i = 0; i < 3; ++i) {
        int yy = y + i - 1;
        if (yy < 0 || yy > 2) continue;
#pragma unroll
        for (int j = 0; j < 3; ++j) {
          int xx = x + j - 1;
          if (xx < 0 || xx > 2) continue;
          s = fmaf(k[i * 3 + j], in[yy * 3 + xx], s);
        }
      }
      out[y * 3 + x] = s;
    }
}

// ---------------- bicubic resize (jax.image.resize, antialias=False) ----------------
__device__ __forceinline__ void mkw(int k0, int IS, float w[4], int k[4]) {
  const float W4[4] = {-0.0625f, 0.5625f, 0.5625f, -0.0625f};
  float ssum = 0.f;
#pragma unroll
  for (int u = 0; u < 4; ++u) {
    int kk = k0 + u;
    bool v = (kk >= 0) && (kk < IS);
    w[u] = v ? W4[u] : 0.f;
    k[u] = v ? kk : 0;
    ssum += w[u];
  }
  float inv = 1.f / ssum;  // interior: ssum == 1.0 exactly
#pragma unroll
  for (int u = 0; u < 4; ++u) w[u] *= inv;
}

__global__ void resize_kernel(const float* __restrict__ src, float* __restrict__ dst,
                              int OS, int step, int koff) {
  int o = blockIdx.x * blockDim.x + threadIdx.x;
  int total = BATCH * 3 * OS * OS;
  if (o >= total) return;
  int j = o % OS;
  int i = (o / OS) % OS;
  int bc = o / (OS * OS);
  const float* s = src + (size_t)bc * IMG * IMG;
  float wr[4], wc[4];
  int kr[4], kc[4];
  mkw(step * i + koff, IMG, wr, kr);
  mkw(step * j + koff, IMG, wc, kc);
  float acc = 0.f;
#pragma unroll
  for (int u = 0; u < 4; ++u) {
    const float* srow = s + (size_t)kr[u] * IMG;
    float rsum = 0.f;
#pragma unroll
    for (int v = 0; v < 4; ++v) rsum = fmaf(wc[v], srow[kc[v]], rsum);
    acc = fmaf(wr[u], rsum, acc);
  }
  dst[o] = acc;
}

// ---------------- patch -> structure tensor -> normalized 27-vector ----------------
template <bool WRITE_C>
__global__ void patch_kernel(const float* __restrict__ img, int H, int Wb,
                             float* __restrict__ dst, int dstBstride, int dstOff,
                             int npp) {
  int g = blockIdx.x * blockDim.x + threadIdx.x;
  if (g >= BATCH * npp) return;
  int b = g / npp, p = g - b * npp;
  int hb = p / Wb, wb = p - hb * Wb;
  const size_t plane = (size_t)H * H;
  const float* base = img + (size_t)b * 3 * plane + (size_t)(hb * 3) * H + wb * 3;

  float gray[9];
#pragma unroll
  for (int y = 0; y < 3; ++y)
#pragma unroll
    for (int x = 0; x < 3; ++x) {
      float r  = base[(size_t)y * H + x];
      float gg = base[plane + (size_t)y * H + x];
      float bl = base[2 * plane + (size_t)y * H + x];
      gray[y * 3 + x] = fmaf(0.114f, bl, fmaf(0.587f, gg, 0.2989f * r));
    }

  // KX = outer(g_s, dg_s), KY = outer(dg_s, g_s), KS = outer(g_r, g_r)
  const float KX[9] = {GA * GA, 0.f, -GA * GA, GB * GA, 0.f, -GB * GA, GA * GA, 0.f, -GA * GA};
  const float KY[9] = {GA * GA, GA * GB, GA * GA, 0.f, 0.f, 0.f, -GA * GA, -GA * GB, -GA * GA};
  const float KS[9] = {RC * RC, RC * RD, RC * RC, RD * RC, RD * RD, RD * RC, RC * RC, RC * RD, RC * RC};

  float Ix[9], Iy[9];
  conv3(gray, KX, Ix);
  conv3(gray, KY, Iy);
  float Pxx[9], Pyy[9], Pxy[9];
#pragma unroll
  for (int t = 0; t < 9; ++t) {
    Pxx[t] = Ix[t] * Ix[t];
    Pyy[t] = Iy[t] * Iy[t];
    Pxy[t] = Ix[t] * Iy[t];
  }
  float st[27];
  conv3(Pxx, KS, st + 0);
  conv3(Pyy, KS, st + 9);
  conv3(Pxy, KS, st + 18);

  float s2 = 0.f;
#pragma unroll
  for (int d = 0; d < 27; ++d) s2 = fmaf(st[d], st[d], s2);
  float nrm = sqrtf(s2) + 1e-12f;
  float inv = 1.0f / nrm;

  float* orow = dst + ((size_t)b * dstBstride + dstOff + p) * RS;
  float cs = 0.f;
#pragma unroll
  for (int d = 0; d < 27; ++d) {
    float v = st[d] * inv;
    orow[d] = v;
    cs = fmaf(v, v, cs);
  }
  if (WRITE_C) orow[27] = cs;
}

// ---------------- chunked argmax of t = q.c_m - |c_m|^2  (== argmin of score) ----------------
__global__ void __launch_bounds__(E_BLOCK) argmin_chunk_kernel(
    const float* __restrict__ p1, const float* __restrict__ p2c,
    float* __restrict__ pscore, int* __restrict__ pidx) {
  int bx = blockIdx.x;  // n-tile [0, E_NT)
  int ms = blockIdx.y;  // m-chunk [0, E_MS)
  int b  = blockIdx.z;
  int t  = threadIdx.x;
  int n0 = bx * E_NPB + t;  // rows n0 and n0+256

  float q0[27], q1[27];
  {
    const float* p1r0 = p1 + ((size_t)b * NP1 + n0) * RS;
    const float* p2r0 = p2c + ((size_t)b * MALL + n0) * RS;
#pragma unroll
    for (int d = 0; d < 27; ++d) q0[d] = p1r0[d] + p2r0[d];
    const float* p1r1 = p1r0 + (size_t)256 * RS;
    const float* p2r1 = p2r0 + (size_t)256 * RS;
#pragma unroll
    for (int d = 0; d < 27; ++d) q1[d] = p1r1[d] + p2r1[d];
  }

  int mbase = ms * E_MC;
  const float* pr = p2c + ((size_t)b * MALL + mbase) * RS;
  float best0 = -INFINITY, best1 = -INFINITY;
  int bi0 = mbase, bi1 = mbase;
  for (int mi = 0; mi < E_MC; ++mi) {
    const float* row = pr + (size_t)mi * RS;
    float cm = row[27];
    float t0 = -cm, t1 = -cm;
#pragma unroll
    for (int d = 0; d < 27; ++d) {
      float pv = row[d];
      t0 = fmaf(q0[d], pv, t0);
      t1 = fmaf(q1[d], pv, t1);
    }
    bool g0 = t0 > best0;
    best0 = g0 ? t0 : best0;
    bi0 = g0 ? (mbase + mi) : bi0;
    bool g1 = t1 > best1;
    best1 = g1 ? t1 : best1;
    bi1 = g1 ? (mbase + mi) : bi1;
  }
  size_t o0 = ((size_t)b * NP1 + n0) * E_MS + ms;
  pscore[o0] = best0;
  pidx[o0] = bi0;
  size_t o1 = o0 + (size_t)256 * E_MS;
  pscore[o1] = best1;
  pidx[o1] = bi1;
}

// ---------------- combine partials, gather selected patch, L1 partial sums ----------------
__global__ void finalize_kernel(const float* __restrict__ p1, const float* __restrict__ p2c,
                                const float* __restrict__ pscore, const int* __restrict__ pidx,
                                float* __restrict__ bsum) {
  int g = blockIdx.x * 256 + threadIdx.x;  // [0, BATCH*NP1)
  float bt = -INFINITY;
  int bi = 0;
  for (int ms = 0; ms < E_MS; ++ms) {
    float s = pscore[(size_t)g * E_MS + ms];
    int ix = pidx[(size_t)g * E_MS + ms];
    bool gg = s > bt;   // ascending-m chunk order + strict '>' => first-argmin tie-break
    bt = gg ? s : bt;
    bi = gg ? ix : bi;
  }
  int b = g >> 12;
  const float* a = p1 + (size_t)g * RS;
  const float* s2 = p2c + ((size_t)b * MALL + bi) * RS;
  float acc = 0.f;
#pragma unroll
  for (int d = 0; d < 27; ++d) acc += fabsf(a[d] - s2[d]);

  __shared__ float red[256];
  red[threadIdx.x] = acc;
  __syncthreads();
  for (int st = 128; st > 0; st >>= 1) {
    if (threadIdx.x < st) red[threadIdx.x] += red[threadIdx.x + st];
    __syncthreads();
  }
  if (threadIdx.x == 0) bsum[blockIdx.x] = red[0];
}

__global__ void final_sum_kernel(const float* __restrict__ bsum, float* __restrict__ out) {
  __shared__ float red[64];
  red[threadIdx.x] = bsum[threadIdx.x];
  __syncthreads();
  for (int st = 32; st > 0; st >>= 1) {
    if (threadIdx.x < st) red[threadIdx.x] += red[threadIdx.x + st];
    __syncthreads();
  }
  if (threadIdx.x == 0) out[0] = red[0] * (1.0f / 442368.0f);
}

}  // namespace

extern "C" void kernel_launch(void* const* d_in, const int* in_sizes, int n_in,
                              void* d_out, int out_size, void* d_ws, size_t ws_size,
                              hipStream_t stream) {
  const float* x  = (const float*)d_in[0];
  const float* gt = (const float*)d_in[1];
  float* out = (float*)d_out;

  // workspace layout (floats)
  float* ws = (float*)d_ws;
  float* p1   = ws;                               // 4*4096*28 = 458752
  float* p2c  = p1 + (size_t)BATCH * NP1 * RS;    // 4*5376*28 = 602112
  float* r96  = p2c + (size_t)BATCH * MALL * RS;  // 4*3*96*96 = 110592
  float* r48  = r96 + (size_t)BATCH * 3 * 96 * 96;  // 27648
  float* pscore = r48 + (size_t)BATCH * 3 * 48 * 48;           // 4*4096*32
  int*   pidx   = (int*)(pscore + (size_t)BATCH * NP1 * E_MS); // 4*4096*32
  float* bsum   = (float*)(pidx + (size_t)BATCH * NP1 * E_MS); // 64

  // resize gt -> 96 and 48 (bicubic, antialias=False)
  {
    int tot = BATCH * 3 * 96 * 96;
    resize_kernel<<<(tot + 255) / 256, 256, 0, stream>>>(gt, r96, 96, 2, -1);
  }
  {
    int tot = BATCH * 3 * 48 * 48;
    resize_kernel<<<(tot + 255) / 256, 256, 0, stream>>>(gt, r48, 48, 4, 0);
  }

  // patches
  patch_kernel<false><<<(BATCH * NP1 + 255) / 256, 256, 0, stream>>>(
      x, IMG, 64, p1, NP1, 0, NP1);
  patch_kernel<true><<<(BATCH * NP1 + 255) / 256, 256, 0, stream>>>(
      gt, IMG, 64, p2c, MALL, 0, NP1);
  patch_kernel<true><<<(BATCH * 1024 + 255) / 256, 256, 0, stream>>>(
      r96, 96, 32, p2c, MALL, NP1, 1024);
  patch_kernel<true><<<(BATCH * 256 + 255) / 256, 256, 0, stream>>>(
      r48, 48, 16, p2c, MALL, NP1 + 1024, 256);

  // chunked argmax
  {
    dim3 grid(E_NT, E_MS, BATCH);
    argmin_chunk_kernel<<<grid, E_BLOCK, 0, stream>>>(p1, p2c, pscore, pidx);
  }

  // finalize: combine chunks + L1 loss partials
  finalize_kernel<<<(BATCH * NP1) / 256, 256, 0, stream>>>(p1, p2c, pscore, pidx, bsum);
  final_sum_kernel<<<1, 64, 0, stream>>>(bsum, out);
}

// Round 2
// 73.882 us; speedup vs baseline: 1.4351x; 1.4351x over previous
//
#include <hip/hip_runtime.h>
#include <hip/hip_bf16.h>
#include <math.h>

// ---------------- problem constants ----------------
namespace {
constexpr int BATCH = 4;
constexpr int IMG   = 192;
constexpr int NP1   = 4096;   // 64*64 full-res patches per image
constexpr int MALL  = 5376;   // 4096 + 1024 + 256 candidate patches
constexpr int RS    = 28;     // fp32 row stride: 27 values + |c|^2 slot
constexpr int NCHUNK = 16;    // m-chunks for argmin partials
constexpr int TPC    = 21;    // 16-wide m-tiles per chunk (16*21*16 = 5376)

// gaussian kernel constants (float32 images of the numpy float32 values)
#define GA 0.27406862f   // gauss1d(1.0) edge
#define GB 0.45186276f   // gauss1d(1.0) center
#define RC 0.33277732f   // gauss1d(10.0) edge
#define RD 0.33444537f   // gauss1d(10.0) center

typedef __bf16 bf16x8 __attribute__((ext_vector_type(8)));
typedef float  f32x4  __attribute__((ext_vector_type(4)));

__device__ __forceinline__ void conv3(const float in[9], const float k[9], float out[9]) {
#pragma unroll
  for (int y = 0; y < 3; ++y)
#pragma unroll
    for (int x = 0; x < 3; ++x) {
      float s = 0.f;
#pragma unroll
      for (int i = 0; i < 3; ++i) {
        int yy = y + i - 1;
        if (yy < 0 || yy > 2) continue;
#pragma unroll
        for (int j = 0; j < 3; ++j) {
          int xx = x + j - 1;
          if (xx < 0 || xx > 2) continue;
          s = fmaf(k[i * 3 + j], in[yy * 3 + xx], s);
        }
      }
      out[y * 3 + x] = s;
    }
}

// ---------------- bicubic resize (jax.image.resize, antialias=False) ----------------
__device__ __forceinline__ void mkw(int k0, int IS, float w[4], int k[4]) {
  const float W4[4] = {-0.0625f, 0.5625f, 0.5625f, -0.0625f};
  float ssum = 0.f;
#pragma unroll
  for (int u = 0; u < 4; ++u) {
    int kk = k0 + u;
    bool v = (kk >= 0) && (kk < IS);
    w[u] = v ? W4[u] : 0.f;
    k[u] = v ? kk : 0;
    ssum += w[u];
  }
  float inv = 1.f / ssum;
#pragma unroll
  for (int u = 0; u < 4; ++u) w[u] *= inv;
}

__global__ void resize_kernel(const float* __restrict__ src, float* __restrict__ dst,
                              int OS, int step, int koff) {
  int o = blockIdx.x * blockDim.x + threadIdx.x;
  int total = BATCH * 3 * OS * OS;
  if (o >= total) return;
  int j = o % OS;
  int i = (o / OS) % OS;
  int bc = o / (OS * OS);
  const float* s = src + (size_t)bc * IMG * IMG;
  float wr[4], wc[4];
  int kr[4], kc[4];
  mkw(step * i + koff, IMG, wr, kr);
  mkw(step * j + koff, IMG, wc, kc);
  float acc = 0.f;
#pragma unroll
  for (int u = 0; u < 4; ++u) {
    const float* srow = s + (size_t)kr[u] * IMG;
    float rsum = 0.f;
#pragma unroll
    for (int v = 0; v < 4; ++v) rsum = fmaf(wc[v], srow[kc[v]], rsum);
    acc = fmaf(wr[u], rsum, acc);
  }
  dst[o] = acc;
}

// ---------------- patch -> structure tensor -> normalized 27-vector ----------------
template <bool WRITE_C>
__global__ void patch_kernel(const float* __restrict__ img, int H, int Wb,
                             float* __restrict__ dst, int dstBstride, int dstOff,
                             int npp) {
  int g = blockIdx.x * blockDim.x + threadIdx.x;
  if (g >= BATCH * npp) return;
  int b = g / npp, p = g - b * npp;
  int hb = p / Wb, wb = p - hb * Wb;
  const size_t plane = (size_t)H * H;
  const float* base = img + (size_t)b * 3 * plane + (size_t)(hb * 3) * H + wb * 3;

  float gray[9];
#pragma unroll
  for (int y = 0; y < 3; ++y)
#pragma unroll
    for (int x = 0; x < 3; ++x) {
      float r  = base[(size_t)y * H + x];
      float gg = base[plane + (size_t)y * H + x];
      float bl = base[2 * plane + (size_t)y * H + x];
      gray[y * 3 + x] = fmaf(0.114f, bl, fmaf(0.587f, gg, 0.2989f * r));
    }

  const float KX[9] = {GA * GA, 0.f, -GA * GA, GB * GA, 0.f, -GB * GA, GA * GA, 0.f, -GA * GA};
  const float KY[9] = {GA * GA, GA * GB, GA * GA, 0.f, 0.f, 0.f, -GA * GA, -GA * GB, -GA * GA};
  const float KS[9] = {RC * RC, RC * RD, RC * RC, RD * RC, RD * RD, RD * RC, RC * RC, RC * RD, RC * RC};

  float Ix[9], Iy[9];
  conv3(gray, KX, Ix);
  conv3(gray, KY, Iy);
  float Pxx[9], Pyy[9], Pxy[9];
#pragma unroll
  for (int t = 0; t < 9; ++t) {
    Pxx[t] = Ix[t] * Ix[t];
    Pyy[t] = Iy[t] * Iy[t];
    Pxy[t] = Ix[t] * Iy[t];
  }
  float st[27];
  conv3(Pxx, KS, st + 0);
  conv3(Pyy, KS, st + 9);
  conv3(Pxy, KS, st + 18);

  float s2 = 0.f;
#pragma unroll
  for (int d = 0; d < 27; ++d) s2 = fmaf(st[d], st[d], s2);
  float nrm = sqrtf(s2) + 1e-12f;
  float inv = 1.0f / nrm;

  float* orow = dst + ((size_t)b * dstBstride + dstOff + p) * RS;
  float cs = 0.f;
#pragma unroll
  for (int d = 0; d < 27; ++d) {
    float v = st[d] * inv;
    orow[d] = v;
    cs = fmaf(v, v, cs);
  }
  if (WRITE_C) orow[27] = cs;
}

// ---------------- pack Q=p1+p2 and C=p2c into bf16 hi/lo rows of 32 ----------------
// Row layout (32 uints = 128 B): uints 0..15 = hi bf16 pairs (k=0..31),
// uints 16..31 = lo bf16 pairs. k=27 carries [1.0 | -|c|^2] so the MFMA
// computes q.c - |c|^2 directly. k=28..31 zero.
__global__ void pack_kernel(const float* __restrict__ p1, const float* __restrict__ p2c,
                            unsigned* __restrict__ Qp, unsigned* __restrict__ Cp) {
  int g = blockIdx.x * 256 + threadIdx.x;
  const int NC = BATCH * MALL;
  float v[28];
  unsigned* dst;
  if (g < NC) {
    const float* s = p2c + (size_t)g * RS;
#pragma unroll
    for (int d = 0; d < 27; ++d) v[d] = s[d];
    v[27] = -s[27];
    dst = Cp + (size_t)g * 32;
  } else {
    int q = g - NC;
    if (q >= BATCH * NP1) return;
    int b = q >> 12, n = q & (NP1 - 1);
    const float* a = p1 + (size_t)q * RS;
    const float* c = p2c + ((size_t)b * MALL + n) * RS;
#pragma unroll
    for (int d = 0; d < 27; ++d) v[d] = a[d] + c[d];
    v[27] = 1.0f;
    dst = Qp + (size_t)q * 32;
  }

  unsigned uh[16], ul[16];
#pragma unroll
  for (int p = 0; p < 16; ++p) {
    float a  = (2 * p < 28) ? v[2 * p] : 0.f;
    float bb = (2 * p + 1 < 28) ? v[2 * p + 1] : 0.f;
    __hip_bfloat16 ah = __float2bfloat16(a);
    __hip_bfloat16 bh = __float2bfloat16(bb);
    float af = __bfloat162float(ah), bf2 = __bfloat162float(bh);
    __hip_bfloat16 al = __float2bfloat16(a - af);
    __hip_bfloat16 bl = __float2bfloat16(bb - bf2);
    uh[p] = ((unsigned)__builtin_bit_cast(unsigned short, bh) << 16) |
            (unsigned)__builtin_bit_cast(unsigned short, ah);
    ul[p] = ((unsigned)__builtin_bit_cast(unsigned short, bl) << 16) |
            (unsigned)__builtin_bit_cast(unsigned short, al);
  }
  uint4* d4 = reinterpret_cast<uint4*>(dst);
  d4[0] = make_uint4(uh[0], uh[1], uh[2], uh[3]);
  d4[1] = make_uint4(uh[4], uh[5], uh[6], uh[7]);
  d4[2] = make_uint4(uh[8], uh[9], uh[10], uh[11]);
  d4[3] = make_uint4(uh[12], uh[13], uh[14], uh[15]);
  d4[4] = make_uint4(ul[0], ul[1], ul[2], ul[3]);
  d4[5] = make_uint4(ul[4], ul[5], ul[6], ul[7]);
  d4[6] = make_uint4(ul[8], ul[9], ul[10], ul[11]);
  d4[7] = make_uint4(ul[12], ul[13], ul[14], ul[15]);
}

// ---------------- MFMA argmax of t = q.c - |c|^2 over m (bf16x3 split) ----------------
// Wave: 4 n-tiles (64 rows). Grid: (rowgroup=16, chunk=16, batch=4), 256 thr.
// D mapping (16x16x32): col = lane&15 (m within tile), row = (lane>>4)*4 + reg.
__global__ void __launch_bounds__(256, 4) argmin_mfma_kernel(
    const unsigned* __restrict__ Qp, const unsigned* __restrict__ Cp,
    float* __restrict__ pscore, int* __restrict__ pidx) {
  const int lane = threadIdx.x & 63;
  const int w = threadIdx.x >> 6;
  const int chunk = blockIdx.y;
  const int b = blockIdx.z;
  const int nbase = blockIdx.x * 256 + w * 64;
  const int lm = lane & 15, lg = lane >> 4;

  bf16x8 qh[4], ql[4];
#pragma unroll
  for (int t = 0; t < 4; ++t) {
    const unsigned* rp = Qp + ((size_t)(b * NP1 + nbase + t * 16 + lm)) * 32 + lg * 4;
    qh[t] = *reinterpret_cast<const bf16x8*>(rp);
    ql[t] = *reinterpret_cast<const bf16x8*>(rp + 16);
  }

  float best[4][4];
  int idx[4][4];
#pragma unroll
  for (int t = 0; t < 4; ++t)
#pragma unroll
    for (int r = 0; r < 4; ++r) { best[t][r] = -INFINITY; idx[t][r] = 0; }

  const int tile0 = chunk * TPC;
  for (int i = 0; i < TPC; ++i) {
    const int m0 = (tile0 + i) * 16;
    const unsigned* cr = Cp + ((size_t)(b * MALL + m0 + lm)) * 32 + lg * 4;
    bf16x8 ch = *reinterpret_cast<const bf16x8*>(cr);
    bf16x8 cl = *reinterpret_cast<const bf16x8*>(cr + 16);
    const int mi = m0 + lm;
#pragma unroll
    for (int t = 0; t < 4; ++t) {
      f32x4 a = {0.f, 0.f, 0.f, 0.f};
      a = __builtin_amdgcn_mfma_f32_16x16x32_bf16(qh[t], ch, a, 0, 0, 0);
      a = __builtin_amdgcn_mfma_f32_16x16x32_bf16(ql[t], ch, a, 0, 0, 0);
      a = __builtin_amdgcn_mfma_f32_16x16x32_bf16(qh[t], cl, a, 0, 0, 0);
#pragma unroll
      for (int r = 0; r < 4; ++r) {
        bool g = a[r] > best[t][r];
        best[t][r] = g ? a[r] : best[t][r];
        idx[t][r] = g ? mi : idx[t][r];
      }
    }
  }

  // reduce (best, idx) across the 16 lanes of each row-group; min idx on ties
#pragma unroll
  for (int t = 0; t < 4; ++t)
#pragma unroll
    for (int r = 0; r < 4; ++r) {
      float bv = best[t][r];
      int bi = idx[t][r];
#pragma unroll
      for (int mk = 1; mk < 16; mk <<= 1) {
        float ov = __shfl_xor(bv, mk, 64);
        int oi = __shfl_xor(bi, mk, 64);
        bool take = (ov > bv) || (ov == bv && oi < bi);
        bv = take ? ov : bv;
        bi = take ? oi : bi;
      }
      if (lm == 0) {
        int row = nbase + t * 16 + lg * 4 + r;
        size_t o = ((size_t)(b * NP1 + row)) * NCHUNK + chunk;
        pscore[o] = bv;
        pidx[o] = bi;
      }
    }
}

// ---------------- combine partials, gather selected patch, L1 partial sums ----------------
__global__ void finalize_kernel(const float* __restrict__ p1, const float* __restrict__ p2c,
                                const float* __restrict__ pscore, const int* __restrict__ pidx,
                                float* __restrict__ bsum) {
  int g = blockIdx.x * 256 + threadIdx.x;  // [0, BATCH*NP1)
  float bt = -INFINITY;
  int bi = 0;
  for (int ms = 0; ms < NCHUNK; ++ms) {
    float s = pscore[(size_t)g * NCHUNK + ms];
    int ix = pidx[(size_t)g * NCHUNK + ms];
    bool gg = (s > bt) || (s == bt && ix < bi);  // ascending m + min-idx tie-break
    bt = gg ? s : bt;
    bi = gg ? ix : bi;
  }
  int b = g >> 12;
  const float* a = p1 + (size_t)g * RS;
  const float* s2 = p2c + ((size_t)b * MALL + bi) * RS;
  float acc = 0.f;
#pragma unroll
  for (int d = 0; d < 27; ++d) acc += fabsf(a[d] - s2[d]);

  __shared__ float red[256];
  red[threadIdx.x] = acc;
  __syncthreads();
  for (int st = 128; st > 0; st >>= 1) {
    if (threadIdx.x < st) red[threadIdx.x] += red[threadIdx.x + st];
    __syncthreads();
  }
  if (threadIdx.x == 0) bsum[blockIdx.x] = red[0];
}

__global__ void final_sum_kernel(const float* __restrict__ bsum, float* __restrict__ out) {
  __shared__ float red[64];
  red[threadIdx.x] = bsum[threadIdx.x];
  __syncthreads();
  for (int st = 32; st > 0; st >>= 1) {
    if (threadIdx.x < st) red[threadIdx.x] += red[threadIdx.x + st];
    __syncthreads();
  }
  if (threadIdx.x == 0) out[0] = red[0] * (1.0f / 442368.0f);
}

}  // namespace

extern "C" void kernel_launch(void* const* d_in, const int* in_sizes, int n_in,
                              void* d_out, int out_size, void* d_ws, size_t ws_size,
                              hipStream_t stream) {
  const float* x  = (const float*)d_in[0];
  const float* gt = (const float*)d_in[1];
  float* out = (float*)d_out;

  // workspace layout (4-byte slots)
  float* ws = (float*)d_ws;
  float* p1   = ws;                                   // 4*4096*28 = 458752
  float* p2c  = p1 + (size_t)BATCH * NP1 * RS;        // 4*5376*28 = 602112
  float* r96  = p2c + (size_t)BATCH * MALL * RS;      // 110592
  float* r48  = r96 + (size_t)BATCH * 3 * 96 * 96;    // 27648
  unsigned* Qp = (unsigned*)(r48 + (size_t)BATCH * 3 * 48 * 48);  // 4*4096*32 = 524288
  unsigned* Cp = Qp + (size_t)BATCH * NP1 * 32;       // 4*5376*32 = 688128
  float* pscore = (float*)(Cp + (size_t)BATCH * MALL * 32);       // 4*4096*16
  int*   pidx   = (int*)(pscore + (size_t)BATCH * NP1 * NCHUNK);  // 4*4096*16
  float* bsum   = (float*)(pidx + (size_t)BATCH * NP1 * NCHUNK);  // 64

  // resize gt -> 96 and 48 (bicubic, antialias=False)
  {
    int tot = BATCH * 3 * 96 * 96;
    resize_kernel<<<(tot + 255) / 256, 256, 0, stream>>>(gt, r96, 96, 2, -1);
  }
  {
    int tot = BATCH * 3 * 48 * 48;
    resize_kernel<<<(tot + 255) / 256, 256, 0, stream>>>(gt, r48, 48, 4, 0);
  }

  // patches
  patch_kernel<false><<<(BATCH * NP1 + 255) / 256, 256, 0, stream>>>(
      x, IMG, 64, p1, NP1, 0, NP1);
  patch_kernel<true><<<(BATCH * NP1 + 255) / 256, 256, 0, stream>>>(
      gt, IMG, 64, p2c, MALL, 0, NP1);
  patch_kernel<true><<<(BATCH * 1024 + 255) / 256, 256, 0, stream>>>(
      r96, 96, 32, p2c, MALL, NP1, 1024);
  patch_kernel<true><<<(BATCH * 256 + 255) / 256, 256, 0, stream>>>(
      r48, 48, 16, p2c, MALL, NP1 + 1024, 256);

  // pack bf16 hi/lo operands (Q = p1+p2 with k27=1; C = p2c with k27=-|c|^2)
  {
    int tot = BATCH * (MALL + NP1);
    pack_kernel<<<(tot + 255) / 256, 256, 0, stream>>>(p1, p2c, Qp, Cp);
  }

  // MFMA chunked argmax
  {
    dim3 grid(16, NCHUNK, BATCH);
    argmin_mfma_kernel<<<grid, 256, 0, stream>>>(Qp, Cp, pscore, pidx);
  }

  // finalize: combine chunks + L1 loss partials
  finalize_kernel<<<(BATCH * NP1) / 256, 256, 0, stream>>>(p1, p2c, pscore, pidx, bsum);
  final_sum_kernel<<<1, 64, 0, stream>>>(bsum, out);
}